// Round 20
// baseline (102.528 us; speedup 1.0000x reference)
//
#include <hip/hip_runtime.h>
#include <math.h>

#define N_NODES 50000
#define IN_CH   128
#define TOT_CH  128          // HEADS*OUT_CH
#define NEDGE   800000
#define ETOT    (NEDGE + N_NODES)
#define MTILES  ((N_NODES + 63) / 64)     // 782
#define NBUCK   ((N_NODES + 255) / 256)   // 196 buckets of 256 nodes
#define BCAP    8192                       // fixed slots per bucket (mean 4352, sigma 66)
#define EPB     4096                       // edges per binning block
#define NBIN    ((ETOT + EPB - 1) / EPB)   // 208

// ---------------- workspace layout (bytes) ----------------
#define OFF_XL      ((size_t)0)                 // bf16 [N][128] = 12.8MB
#define OFF_EBUF    ((size_t)12800000)          // u32 [NBUCK*BCAP] = 6.42MB
#define OFF_XR      ((size_t)25600000)          // bf16 [N][128] = 12.8MB
#define OFF_SRC     ((size_t)38400000)          // int [NBUCK*BCAP] = 6.42MB
#define OFF_BT      ((size_t)44900352)          // Bt bf16-pairs 64KB
#define OFF_GCUR    ((size_t)45000064)          // int [NBUCK]
#define OFF_ROWPTR  ((size_t)51200000)          // int2 [N] = 400KB

typedef float f32x4 __attribute__((ext_vector_type(4)));
typedef short s16x8 __attribute__((ext_vector_type(8)));

__device__ __forceinline__ unsigned f2bf(float f) {   // RNE f32->bf16 bits
    unsigned u = __float_as_uint(f);
    return (u + 0x7fffu + ((u >> 16) & 1u)) >> 16;
}
__device__ __forceinline__ float bflo(unsigned u) { return __uint_as_float(u << 16); }
__device__ __forceinline__ float bfhi(unsigned u) { return __uint_as_float(u & 0xffff0000u); }

__device__ __forceinline__ int SWZ(int row, int byteoff) {
    return row * 256 + (byteoff ^ ((row & 7) << 4));
}

// ============ K_a: wconv (64 blocks) || zero gcur (1 block) ============
__global__ __launch_bounds__(256) void ka_kernel(
    const float* __restrict__ Wl, const float* __restrict__ Wr,
    unsigned* __restrict__ btg, int* __restrict__ gcur)
{
    const int bid = blockIdx.x;
    const int tid = threadIdx.x;
    if (bid == 64) {
        if (tid < NBUCK) gcur[tid] = 0;
        return;
    }
    const int g = bid * 256 + tid;
    const int n = g >> 6, kk = g & 63;
    const float* W = (n < 128) ? Wl : Wr;
    const int nc = n & 127;
    const float a = W[(size_t)(2 * kk) * 128 + nc];
    const float b = W[(size_t)(2 * kk + 1) * 128 + nc];
    btg[g] = f2bf(a) | (f2bf(b) << 16);
}

// ============ K1: binscatter alone (fixed-capacity buckets) ============
__global__ __launch_bounds__(256) void binscatter_kernel(
    const int* __restrict__ ei, int* __restrict__ gcur, unsigned* __restrict__ ebuf)
{
    __shared__ int lcnt[256];
    __shared__ int lbase[256];
    const int bid = blockIdx.x;
    const int tid = threadIdx.x;
    lcnt[tid] = 0;
    __syncthreads();
    const int base = bid * EPB;
    int sv[16], dv[16];
#pragma unroll
    for (int u = 0; u < 16; ++u) {
        const int e = base + u * 256 + tid;
        int s32 = 0, d32 = -1;
        if (e < ETOT) {
            if (e < NEDGE) { s32 = ei[e]; d32 = ei[NEDGE + e]; }
            else           { s32 = d32 = e - NEDGE; }
            atomicAdd(&lcnt[d32 >> 8], 1);
        }
        sv[u] = s32; dv[u] = d32;
    }
    __syncthreads();
    if (tid < NBUCK) {
        const int v = lcnt[tid];
        lbase[tid] = v ? atomicAdd(&gcur[tid], v) : 0;
    }
    __syncthreads();
    lcnt[tid] = 0;
    __syncthreads();
#pragma unroll
    for (int u = 0; u < 16; ++u) {
        const int d32 = dv[u];
        if (d32 >= 0) {
            const int b = d32 >> 8;
            const int p = lbase[b] + atomicAdd(&lcnt[b], 1);
            ebuf[b * BCAP + p] = (unsigned)sv[u] | ((unsigned)(d32 & 255) << 16);
        }
    }
}

// ============ K2: place (196) || MFMA GEMM (782, reg-B, 1 barrier) ============
__global__ __launch_bounds__(256) void k2_kernel(
    const float* __restrict__ x, const unsigned* __restrict__ btg,
    unsigned* __restrict__ xl_bf, unsigned* __restrict__ xr_bf,
    const unsigned* __restrict__ ebuf, const int* __restrict__ gcur,
    int2* __restrict__ rowptr2, int* __restrict__ ssrc)
{
    __shared__ __align__(16) unsigned char smem[16384];
    __shared__ int wsum[4];
    const int bid = blockIdx.x;
    const int tid = threadIdx.x;

    if (bid < NBUCK) {
        // ---- place: derive node ranges within padded bucket region ----
        int* lcnt = (int*)smem;          // [256]
        int* lcur = ((int*)smem) + 256;  // [256]
        const int ecnt  = gcur[bid];
        const int ebase = bid * BCAP;
        lcnt[tid] = 0;
        __syncthreads();
        for (int k = tid; k < ecnt; k += 256)
            atomicAdd(&lcnt[(ebuf[ebase + k] >> 16) & 255], 1);
        __syncthreads();
        const int lane = tid & 63, wid = tid >> 6;
        const int v = lcnt[tid];
        int s = v;
#pragma unroll
        for (int off = 1; off < 64; off <<= 1) {
            int t = __shfl_up(s, off);
            if (lane >= off) s += t;
        }
        if (lane == 63) wsum[wid] = s;
        __syncthreads();
        if (tid == 0) {
            int acc = 0;
#pragma unroll
            for (int w = 0; w < 4; ++w) { int t = wsum[w]; wsum[w] = acc; acc += t; }
        }
        __syncthreads();
        const int gpos = ebase + wsum[wid] + s - v;   // exclusive prefix in bucket
        const int node = (bid << 8) + tid;
        if (node < N_NODES) rowptr2[node] = make_int2(gpos, gpos + v);
        lcur[tid] = gpos;
        __syncthreads();
        for (int k = tid; k < ecnt; k += 256) {
            const unsigned ed = ebuf[ebase + k];
            const int p = atomicAdd(&lcur[(ed >> 16) & 255], 1);
            ssrc[p] = (int)(ed & 0xffffu);
        }
        return;
    }

    // ---- gemm: one 64-row m-tile; A in LDS (once), B fragments from L2 regs ----
    unsigned char* Al = smem;            // 16KB
    const int mt = bid - NBUCK;
    const int mbase = mt * 64;
    const int l  = tid & 63;
    const int wv = tid >> 6;

    {   // stage A (f32 -> bf16, swizzled) -- once
        const int r = tid >> 2, q = tid & 3;
        int gm = mbase + r;
        gm = (gm < N_NODES) ? gm : (N_NODES - 1);
        const float* xrow = x + (size_t)gm * IN_CH + q * 32;
#pragma unroll
        for (int i = 0; i < 8; ++i) {
            const float4 xv = *(const float4*)(xrow + i * 4);
            uint2 p;
            p.x = f2bf(xv.x) | (f2bf(xv.y) << 16);
            p.y = f2bf(xv.z) | (f2bf(xv.w) << 16);
            *(uint2*)(Al + SWZ(r, q * 64 + i * 8)) = p;
        }
    }
    __syncthreads();   // the ONLY barrier

    s16x8 af[4];
#pragma unroll
    for (int ks = 0; ks < 4; ++ks)
        af[ks] = *(const s16x8*)(Al + SWZ(wv * 16 + (l & 15), ks * 64 + (l >> 4) * 16));

#pragma unroll
    for (int nt4 = 0; nt4 < 4; ++nt4) {
        f32x4 acc[4];
#pragma unroll
        for (int n = 0; n < 4; ++n) acc[n] = (f32x4){0.f, 0.f, 0.f, 0.f};
#pragma unroll
        for (int nsub = 0; nsub < 4; ++nsub) {
            // B fragment direct from btg (L2-resident 64KB):
            // col = nt4*64 + nsub*16 + (l&15); k-pairs base = ks*16 + (l>>4)*4
            const unsigned* bcol = btg + (size_t)(nt4 * 64 + nsub * 16 + (l & 15)) * 64 + (l >> 4) * 4;
#pragma unroll
            for (int ks = 0; ks < 4; ++ks) {
                const s16x8 bfr = *(const s16x8*)(bcol + ks * 16);
                acc[nsub] = __builtin_amdgcn_mfma_f32_16x16x32_bf16(af[ks], bfr, acc[nsub], 0, 0, 0);
            }
        }
        unsigned* dstbuf = (nt4 < 2) ? xl_bf : xr_bf;
        const int ncol0 = (nt4 & 1) * 64;
#pragma unroll
        for (int nsub = 0; nsub < 4; ++nsub) {
            const int n = ncol0 + nsub * 16 + (l & 15);
#pragma unroll
            for (int reg = 0; reg < 4; ++reg) {
                const float v  = acc[nsub][reg];
                const float vp = __shfl_xor(v, 1);
                const int row = mbase + wv * 16 + (l >> 4) * 4 + reg;
                if (((l & 1) == 0) && row < N_NODES)
                    dstbuf[(size_t)row * 64 + (n >> 1)] = f2bf(v) | (f2bf(vp) << 16);
            }
        }
    }
}

// ================= K3: fused attention + aggregate (unchanged) =========
#define DPP_ADD(s, ctrl) do { \
        int _t = __builtin_amdgcn_update_dpp(0, __float_as_int(s), ctrl, 0xf, 0xf, true); \
        s += __int_as_float(_t); } while(0)

__global__ __launch_bounds__(256) void gat_kernel(
    const unsigned* __restrict__ xl_bf, const unsigned* __restrict__ xr_bf,
    const int2* __restrict__ rowptr2, const int* __restrict__ srcs,
    const float* __restrict__ att, const float* __restrict__ bias,
    float* __restrict__ out)
{
    const int l  = threadIdx.x & 63;
    const int wv = threadIdx.x >> 6;
    const int sl = l & 15;                       // channel-group lane
    const int q  = l >> 4;                       // quarter = node slot
    const int i  = blockIdx.x * 16 + wv * 4 + q; // this quarter's node (grid exact)
    const int c8 = sl * 8;
    const float LOG2E = 1.4426950408889634f;
    const float K23 = 0.66666669f;               // a4/a6 ratio

    float a6[8], xr8[8];
    {
        const float4 A = *(const float4*)(att + c8);
        const float4 B = *(const float4*)(att + c8 + 4);
        a6[0] = 0.6f * LOG2E * A.x; a6[1] = 0.6f * LOG2E * A.y;
        a6[2] = 0.6f * LOG2E * A.z; a6[3] = 0.6f * LOG2E * A.w;
        a6[4] = 0.6f * LOG2E * B.x; a6[5] = 0.6f * LOG2E * B.y;
        a6[6] = 0.6f * LOG2E * B.z; a6[7] = 0.6f * LOG2E * B.w;
    }
    {
        const uint4 urv = *(const uint4*)(xr_bf + (size_t)i * 64 + sl * 4);
        xr8[0] = bflo(urv.x); xr8[1] = bfhi(urv.x);
        xr8[2] = bflo(urv.y); xr8[3] = bfhi(urv.y);
        xr8[4] = bflo(urv.z); xr8[5] = bfhi(urv.z);
        xr8[6] = bflo(urv.w); xr8[7] = bfhi(urv.w);
    }
    const int2 kr = rowptr2[i];
    int k = kr.x;
    const int kend = kr.y;

    float den = 0.f, b[8];
#pragma unroll
    for (int c = 0; c < 8; ++c) b[c] = 0.f;

    uint4 u;
    {
        const int jv = srcs[k];
        u = *(const uint4*)(xl_bf + (size_t)jv * 64 + sl * 4);
    }
    for (; k < kend; ++k) {
        const uint4 ucur = u;
        {   // prefetch next (clamped)
            const int kn = (k + 1 < kend) ? (k + 1) : k;
            const int jn = srcs[kn];
            u = *(const uint4*)(xl_bf + (size_t)jn * 64 + sl * 4);
        }
        float t[8];
        t[0] = bflo(ucur.x) + xr8[0]; t[1] = bfhi(ucur.x) + xr8[1];
        t[2] = bflo(ucur.y) + xr8[2]; t[3] = bfhi(ucur.y) + xr8[3];
        t[4] = bflo(ucur.z) + xr8[4]; t[5] = bfhi(ucur.z) + xr8[5];
        t[6] = bflo(ucur.w) + xr8[6]; t[7] = bfhi(ucur.w) + xr8[7];
        float s = 0.f;
#pragma unroll
        for (int c = 0; c < 8; ++c) {
            const float h = fmaf(K23, fabsf(t[c]), t[c]);   // t + (2/3)|t|
            s = fmaf(a6[c], h, s);                           // 0.6*att*L2E*leaky
        }
        DPP_ADD(s, 0xB1);   // quad xor1
        DPP_ADD(s, 0x4E);   // quad xor2 -> 4-lane (one head) all-reduce
        const float p = __builtin_amdgcn_exp2f(s);
        den += p;
#pragma unroll
        for (int c = 0; c < 8; ++c) b[c] = fmaf(p, t[c], b[c]);
    }

    const float inv = 1.f / den;
    const float4 bbA = *(const float4*)(bias + c8);
    const float4 bbB = *(const float4*)(bias + c8 + 4);
    float4 o1, o2;
    o1.x = fmaf(b[0], inv, bbA.x - xr8[0]);
    o1.y = fmaf(b[1], inv, bbA.y - xr8[1]);
    o1.z = fmaf(b[2], inv, bbA.z - xr8[2]);
    o1.w = fmaf(b[3], inv, bbA.w - xr8[3]);
    o2.x = fmaf(b[4], inv, bbB.x - xr8[4]);
    o2.y = fmaf(b[5], inv, bbB.y - xr8[5]);
    o2.z = fmaf(b[6], inv, bbB.z - xr8[6]);
    o2.w = fmaf(b[7], inv, bbB.w - xr8[7]);
    *(float4*)(out + (size_t)i * TOT_CH + c8)     = o1;
    *(float4*)(out + (size_t)i * TOT_CH + c8 + 4) = o2;
}

// ================= launch =================
extern "C" void kernel_launch(void* const* d_in, const int* in_sizes, int n_in,
                              void* d_out, int out_size, void* d_ws, size_t ws_size,
                              hipStream_t stream) {
    const float* x    = (const float*)d_in[0];
    const int*   ei   = (const int*)d_in[1];
    const float* Wl   = (const float*)d_in[2];
    const float* Wr   = (const float*)d_in[3];
    const float* att  = (const float*)d_in[4];
    const float* bias = (const float*)d_in[5];
    float* out = (float*)d_out;
    char*  ws  = (char*)d_ws;

    unsigned* xl_bf = (unsigned*)(ws + OFF_XL);
    unsigned* ebuf  = (unsigned*)(ws + OFF_EBUF);
    unsigned* xr_bf = (unsigned*)(ws + OFF_XR);
    int*      ssrc  = (int*)(ws + OFF_SRC);
    unsigned* btg   = (unsigned*)(ws + OFF_BT);
    int*      gcur  = (int*)(ws + OFF_GCUR);
    int2*   rowptr2 = (int2*)(ws + OFF_ROWPTR);

    // K_a: wconv (64) || zero gcur (1)
    hipLaunchKernelGGL(ka_kernel, dim3(65), dim3(256), 0, stream, Wl, Wr, btg, gcur);
    // K1: binscatter (208) alone — R14-proven topology
    hipLaunchKernelGGL(binscatter_kernel, dim3(NBIN), dim3(256), 0, stream, ei, gcur, ebuf);
    // K2: place (196) || gemm (782, reg-B, single barrier)
    hipLaunchKernelGGL(k2_kernel, dim3(NBUCK + MTILES), dim3(256), 0, stream,
                       x, btg, xl_bf, xr_bf, ebuf, gcur, rowptr2, ssrc);
    // K3: gat (one node per quarter-wave)
    hipLaunchKernelGGL(gat_kernel, dim3(N_NODES / 16), dim3(256), 0, stream,
                       xl_bf, xr_bf, rowptr2, ssrc, att, bias, out);
}

// Round 21
// 78.518 us; speedup vs baseline: 1.3058x; 1.3058x over previous
//
#include <hip/hip_runtime.h>
#include <math.h>

#define N_NODES 50000
#define IN_CH   128
#define TOT_CH  128          // HEADS*OUT_CH
#define NEDGE   800000
#define ETOT    (NEDGE + N_NODES)
#define MTILES  ((N_NODES + 63) / 64)     // 782
#define NBUCK   ((N_NODES + 255) / 256)   // 196 buckets of 256 nodes
#define BCAP    8192                       // fixed slots per bucket (mean 4352, sigma 66)
#define EPB     4096                       // edges per binning block
#define NBIN    ((ETOT + EPB - 1) / EPB)   // 208

// ---------------- workspace layout (bytes) ----------------
#define OFF_XL      ((size_t)0)                 // bf16 [N][128] = 12.8MB
#define OFF_EBUF    ((size_t)12800000)          // u32 [NBUCK*BCAP] = 6.42MB
#define OFF_XR      ((size_t)25600000)          // bf16 [N][128] = 12.8MB
#define OFF_SRC     ((size_t)38400000)          // int [NBUCK*BCAP] = 6.42MB
#define OFF_BT      ((size_t)44900352)          // Bt bf16-pairs 64KB
#define OFF_GCUR    ((size_t)45000064)          // int [NBUCK]
#define OFF_ROWPTR  ((size_t)51200000)          // int2 [N] = 400KB

typedef float f32x4 __attribute__((ext_vector_type(4)));
typedef short s16x8 __attribute__((ext_vector_type(8)));

__device__ __forceinline__ unsigned f2bf(float f) {   // RNE f32->bf16 bits
    unsigned u = __float_as_uint(f);
    return (u + 0x7fffu + ((u >> 16) & 1u)) >> 16;
}
__device__ __forceinline__ float bflo(unsigned u) { return __uint_as_float(u << 16); }
__device__ __forceinline__ float bfhi(unsigned u) { return __uint_as_float(u & 0xffff0000u); }

__device__ __forceinline__ int SWZ(int row, int byteoff) {
    return row * 256 + (byteoff ^ ((row & 7) << 4));
}

// ============ K1: binscatter (fixed-capacity buckets) || wconv ============
__global__ __launch_bounds__(256) void k1_kernel(
    const float* __restrict__ Wl, const float* __restrict__ Wr,
    unsigned* __restrict__ btg, const int* __restrict__ ei,
    int* __restrict__ gcur, unsigned* __restrict__ ebuf)
{
    __shared__ int lcnt[256];
    __shared__ int lbase[256];
    const int bid = blockIdx.x;
    const int tid = threadIdx.x;

    if (bid < NBIN) {
        lcnt[tid] = 0;
        __syncthreads();
        const int base = bid * EPB;
        int sv[16], dv[16];
#pragma unroll
        for (int u = 0; u < 16; ++u) {
            const int e = base + u * 256 + tid;
            int s32 = 0, d32 = -1;
            if (e < ETOT) {
                if (e < NEDGE) { s32 = ei[e]; d32 = ei[NEDGE + e]; }
                else           { s32 = d32 = e - NEDGE; }
                atomicAdd(&lcnt[d32 >> 8], 1);
            }
            sv[u] = s32; dv[u] = d32;
        }
        __syncthreads();
        if (tid < NBUCK) {
            const int v = lcnt[tid];
            lbase[tid] = v ? atomicAdd(&gcur[tid], v) : 0;
        }
        __syncthreads();
        lcnt[tid] = 0;
        __syncthreads();
#pragma unroll
        for (int u = 0; u < 16; ++u) {
            const int d32 = dv[u];
            if (d32 >= 0) {
                const int b = d32 >> 8;
                const int p = lbase[b] + atomicAdd(&lcnt[b], 1);
                ebuf[b * BCAP + p] = (unsigned)sv[u] | ((unsigned)(d32 & 255) << 16);
            }
        }
    } else {
        const int g = (bid - NBIN) * 256 + tid;
        if (g < 256 * 64) {
            const int n = g >> 6, kk = g & 63;
            const float* W = (n < 128) ? Wl : Wr;
            const int nc = n & 127;
            const float a = W[(size_t)(2 * kk) * 128 + nc];
            const float b = W[(size_t)(2 * kk + 1) * 128 + nc];
            btg[g] = f2bf(a) | (f2bf(b) << 16);
        }
    }
}

// ============ K2: place || MFMA GEMM (x read ONCE; n-loop inside block) ============
__global__ __launch_bounds__(256) void k2_kernel(
    const float* __restrict__ x, const unsigned* __restrict__ btg,
    unsigned* __restrict__ xl_bf, unsigned* __restrict__ xr_bf,
    const unsigned* __restrict__ ebuf, const int* __restrict__ gcur,
    int2* __restrict__ rowptr2, int* __restrict__ ssrc)
{
    __shared__ __align__(16) unsigned char smem[32768];
    __shared__ int wsum[4];
    const int bid = blockIdx.x;
    const int tid = threadIdx.x;

    if (bid < NBUCK) {
        // ---- place: derive node ranges within padded bucket region ----
        int* lcnt = (int*)smem;          // [256]
        int* lcur = ((int*)smem) + 256;  // [256]
        const int ecnt  = gcur[bid];
        const int ebase = bid * BCAP;
        lcnt[tid] = 0;
        __syncthreads();
        for (int k = tid; k < ecnt; k += 256)
            atomicAdd(&lcnt[(ebuf[ebase + k] >> 16) & 255], 1);
        __syncthreads();
        const int lane = tid & 63, wid = tid >> 6;
        const int v = lcnt[tid];
        int s = v;
#pragma unroll
        for (int off = 1; off < 64; off <<= 1) {
            int t = __shfl_up(s, off);
            if (lane >= off) s += t;
        }
        if (lane == 63) wsum[wid] = s;
        __syncthreads();
        if (tid == 0) {
            int acc = 0;
#pragma unroll
            for (int w = 0; w < 4; ++w) { int t = wsum[w]; wsum[w] = acc; acc += t; }
        }
        __syncthreads();
        const int gpos = ebase + wsum[wid] + s - v;   // exclusive prefix in bucket
        const int node = (bid << 8) + tid;
        if (node < N_NODES) rowptr2[node] = make_int2(gpos, gpos + v);
        lcur[tid] = gpos;
        __syncthreads();
        for (int k = tid; k < ecnt; k += 256) {
            const unsigned ed = ebuf[ebase + k];
            const int p = atomicAdd(&lcur[(ed >> 16) & 255], 1);
            ssrc[p] = (int)(ed & 0xffffu);
        }
        return;
    }

    // ---- gemm: one 64-row m-tile; loop over 4 n-subtiles (x staged ONCE) ----
    unsigned char* Al = smem;            // 16KB
    unsigned char* Bl = smem + 16384;    // 16KB (re-staged per n-tile)
    const int mt = bid - NBUCK;
    const int mbase = mt * 64;
    const int l  = tid & 63;
    const int wv = tid >> 6;

    {   // stage A (f32 -> bf16, swizzled) -- once
        const int r = tid >> 2, q = tid & 3;
        int gm = mbase + r;
        gm = (gm < N_NODES) ? gm : (N_NODES - 1);
        const float* xrow = x + (size_t)gm * IN_CH + q * 32;
#pragma unroll
        for (int i = 0; i < 8; ++i) {
            const float4 xv = *(const float4*)(xrow + i * 4);
            uint2 p;
            p.x = f2bf(xv.x) | (f2bf(xv.y) << 16);
            p.y = f2bf(xv.z) | (f2bf(xv.w) << 16);
            *(uint2*)(Al + SWZ(r, q * 64 + i * 8)) = p;
        }
    }
    {   // stage B tile 0
        const int r = tid >> 2, q = tid & 3;
        const unsigned* brow = btg + (size_t)r * 64 + q * 16;
#pragma unroll
        for (int i = 0; i < 4; ++i) {
            const uint4 v = *(const uint4*)(brow + i * 4);
            *(uint4*)(Bl + SWZ(r, q * 64 + i * 16)) = v;
        }
    }
    __syncthreads();

    s16x8 af[4];
#pragma unroll
    for (int ks = 0; ks < 4; ++ks)
        af[ks] = *(const s16x8*)(Al + SWZ(wv * 16 + (l & 15), ks * 64 + (l >> 4) * 16));

    for (int nt4 = 0; nt4 < 4; ++nt4) {
        f32x4 acc[4];
#pragma unroll
        for (int n = 0; n < 4; ++n) acc[n] = (f32x4){0.f, 0.f, 0.f, 0.f};
#pragma unroll
        for (int nsub = 0; nsub < 4; ++nsub) {
#pragma unroll
            for (int ks = 0; ks < 4; ++ks) {
                const s16x8 bfr = *(const s16x8*)(Bl + SWZ(nsub * 16 + (l & 15), ks * 64 + (l >> 4) * 16));
                acc[nsub] = __builtin_amdgcn_mfma_f32_16x16x32_bf16(af[ks], bfr, acc[nsub], 0, 0, 0);
            }
        }
        // epilogue for this 64-col tile
        unsigned* dstbuf = (nt4 < 2) ? xl_bf : xr_bf;
        const int ncol0 = (nt4 & 1) * 64;
#pragma unroll
        for (int nsub = 0; nsub < 4; ++nsub) {
            const int n = ncol0 + nsub * 16 + (l & 15);
#pragma unroll
            for (int reg = 0; reg < 4; ++reg) {
                const float v  = acc[nsub][reg];
                const float vp = __shfl_xor(v, 1);
                const int row = mbase + wv * 16 + (l >> 4) * 4 + reg;
                if (((l & 1) == 0) && row < N_NODES)
                    dstbuf[(size_t)row * 64 + (n >> 1)] = f2bf(v) | (f2bf(vp) << 16);
            }
        }
        if (nt4 == 3) break;
        __syncthreads();   // all waves done reading Bl
        {   // stage B tile nt4+1
            const int r = tid >> 2, q = tid & 3;
            const unsigned* brow = btg + (size_t)((nt4 + 1) * 64 + r) * 64 + q * 16;
#pragma unroll
            for (int i = 0; i < 4; ++i) {
                const uint4 v = *(const uint4*)(brow + i * 4);
                *(uint4*)(Bl + SWZ(r, q * 64 + i * 16)) = v;
            }
        }
        __syncthreads();
    }
}

// ================= K3: fused attention + aggregate (one wave per dst) =========
#define DPP_ADD(s, ctrl) do { \
        int _t = __builtin_amdgcn_update_dpp(0, __float_as_int(s), ctrl, 0xf, 0xf, true); \
        s += __int_as_float(_t); } while(0)

#define RED16x8(a0,a1,a2,a3,a4,a5,a6,a7) do { \
        DPP_ADD(a0,0xB1); DPP_ADD(a1,0xB1); DPP_ADD(a2,0xB1); DPP_ADD(a3,0xB1); \
        DPP_ADD(a4,0xB1); DPP_ADD(a5,0xB1); DPP_ADD(a6,0xB1); DPP_ADD(a7,0xB1); \
        DPP_ADD(a0,0x4E); DPP_ADD(a1,0x4E); DPP_ADD(a2,0x4E); DPP_ADD(a3,0x4E); \
        DPP_ADD(a4,0x4E); DPP_ADD(a5,0x4E); DPP_ADD(a6,0x4E); DPP_ADD(a7,0x4E); \
        DPP_ADD(a0,0x124); DPP_ADD(a1,0x124); DPP_ADD(a2,0x124); DPP_ADD(a3,0x124); \
        DPP_ADD(a4,0x124); DPP_ADD(a5,0x124); DPP_ADD(a6,0x124); DPP_ADD(a7,0x124); \
        DPP_ADD(a0,0x128); DPP_ADD(a1,0x128); DPP_ADD(a2,0x128); DPP_ADD(a3,0x128); \
        DPP_ADD(a4,0x128); DPP_ADD(a5,0x128); DPP_ADD(a6,0x128); DPP_ADD(a7,0x128); } while(0)

template<bool MASKED>
__device__ __forceinline__ void batch8(
    const int* __restrict__ srcs, int k, int k1, int lane,
    const unsigned* __restrict__ xl_bf,
    float xr2x, float xr2y, float a6x, float a4x, float a6y, float a4y,
    float& den, float& b0, float& b1)
{
#define KIDX(n) (MASKED ? min(k + n, k1 - 1) : (k + n))
#define LOADU(n) \
    const int j##n = __builtin_amdgcn_readfirstlane(srcs[KIDX(n)]); \
    const unsigned u##n = *(xl_bf + (size_t)j##n * 64 + lane);
    LOADU(0); LOADU(1); LOADU(2); LOADU(3);
    LOADU(4); LOADU(5); LOADU(6); LOADU(7);
#undef LOADU
#undef KIDX
#define SCORE(n) \
    const float t0_##n = bflo(u##n) + xr2x; \
    const float t1_##n = bfhi(u##n) + xr2y; \
    float s##n = fmaf(a6x, t0_##n, fmaf(a4x, fabsf(t0_##n), \
                 fmaf(a6y, t1_##n, a4y * fabsf(t1_##n))));
    SCORE(0); SCORE(1); SCORE(2); SCORE(3);
    SCORE(4); SCORE(5); SCORE(6); SCORE(7);
#undef SCORE
    RED16x8(s0, s1, s2, s3, s4, s5, s6, s7);
    if (MASKED) {
        const int r = k1 - k;     // valid slots, >=1
        s1 = (1 < r) ? s1 : -1e30f;
        s2 = (2 < r) ? s2 : -1e30f;
        s3 = (3 < r) ? s3 : -1e30f;
        s4 = (4 < r) ? s4 : -1e30f;
        s5 = (5 < r) ? s5 : -1e30f;
        s6 = (6 < r) ? s6 : -1e30f;
        s7 = (7 < r) ? s7 : -1e30f;
    }
    const float p0 = __builtin_amdgcn_exp2f(s0), p1 = __builtin_amdgcn_exp2f(s1);
    const float p2 = __builtin_amdgcn_exp2f(s2), p3 = __builtin_amdgcn_exp2f(s3);
    const float p4 = __builtin_amdgcn_exp2f(s4), p5 = __builtin_amdgcn_exp2f(s5);
    const float p6 = __builtin_amdgcn_exp2f(s6), p7 = __builtin_amdgcn_exp2f(s7);
    den += ((p0 + p1) + (p2 + p3)) + ((p4 + p5) + (p6 + p7));
    {
        const float e0 = fmaf(p1, t0_1, p0 * t0_0);
        const float e1 = fmaf(p3, t0_3, p2 * t0_2);
        const float e2 = fmaf(p5, t0_5, p4 * t0_4);
        const float e3 = fmaf(p7, t0_7, p6 * t0_6);
        b0 += (e0 + e1) + (e2 + e3);
        const float f0 = fmaf(p1, t1_1, p0 * t1_0);
        const float f1 = fmaf(p3, t1_3, p2 * t1_2);
        const float f2 = fmaf(p5, t1_5, p4 * t1_4);
        const float f3 = fmaf(p7, t1_7, p6 * t1_6);
        b1 += (f0 + f1) + (f2 + f3);
    }
}

__global__ __launch_bounds__(256) void gat_kernel(
    const unsigned* __restrict__ xl_bf, const unsigned* __restrict__ xr_bf,
    const int2* __restrict__ rowptr2, const int* __restrict__ srcs,
    const float* __restrict__ att, const float* __restrict__ bias,
    float* __restrict__ out)
{
    const int lane = threadIdx.x & 63;
    const int i = blockIdx.x * 4 + (threadIdx.x >> 6);
    if (i >= N_NODES) return;
    const int c = lane * 2;
    const float2 att2 = *(const float2*)(att + c);
    const unsigned ur = xr_bf[(size_t)i * 64 + lane];
    const float xr2x = bflo(ur), xr2y = bfhi(ur);
    const float LOG2E = 1.4426950408889634f;
    const float a6x = 0.6f * att2.x * LOG2E, a4x = 0.4f * att2.x * LOG2E;
    const float a6y = 0.6f * att2.y * LOG2E, a4y = 0.4f * att2.y * LOG2E;
    const int2 kr = rowptr2[i];
    const int k0 = __builtin_amdgcn_readfirstlane(kr.x);   // scalarize -> s_load path
    const int k1 = __builtin_amdgcn_readfirstlane(kr.y);

    float den = 0.f, b0 = 0.f, b1 = 0.f;
    int k = k0;
    for (; k + 8 <= k1; k += 8)
        batch8<false>(srcs, k, k1, lane, xl_bf, xr2x, xr2y,
                      a6x, a4x, a6y, a4y, den, b0, b1);
    if (k < k1)
        batch8<true>(srcs, k, k1, lane, xl_bf, xr2x, xr2y,
                     a6x, a4x, a6y, a4y, den, b0, b1);

    const float inv = 1.f / den;
    const float2 bb = *(const float2*)(bias + c);
    float2 o;
    o.x = fmaf(b0, inv, bb.x - xr2x);
    o.y = fmaf(b1, inv, bb.y - xr2y);
    *(float2*)(out + (size_t)i * TOT_CH + c) = o;
}

// ================= launch =================
extern "C" void kernel_launch(void* const* d_in, const int* in_sizes, int n_in,
                              void* d_out, int out_size, void* d_ws, size_t ws_size,
                              hipStream_t stream) {
    const float* x    = (const float*)d_in[0];
    const int*   ei   = (const int*)d_in[1];
    const float* Wl   = (const float*)d_in[2];
    const float* Wr   = (const float*)d_in[3];
    const float* att  = (const float*)d_in[4];
    const float* bias = (const float*)d_in[5];
    float* out = (float*)d_out;
    char*  ws  = (char*)d_ws;

    unsigned* xl_bf = (unsigned*)(ws + OFF_XL);
    unsigned* ebuf  = (unsigned*)(ws + OFF_EBUF);
    unsigned* xr_bf = (unsigned*)(ws + OFF_XR);
    int*      ssrc  = (int*)(ws + OFF_SRC);
    unsigned* btg   = (unsigned*)(ws + OFF_BT);
    int*      gcur  = (int*)(ws + OFF_GCUR);
    int2*   rowptr2 = (int2*)(ws + OFF_ROWPTR);

    hipMemsetAsync(gcur, 0, NBUCK * sizeof(int), stream);
    // K1: binscatter (208) || wconv (64)
    hipLaunchKernelGGL(k1_kernel, dim3(NBIN + 64), dim3(256), 0, stream,
                       Wl, Wr, btg, ei, gcur, ebuf);
    // K2: place (196, first) || gemm (782, x staged once per m-tile)
    hipLaunchKernelGGL(k2_kernel, dim3(NBUCK + MTILES), dim3(256), 0, stream,
                       x, btg, xl_bf, xr_bf, ebuf, gcur, rowptr2, ssrc);
    // K3: gat
    hipLaunchKernelGGL(gat_kernel, dim3((N_NODES + 3) / 4), dim3(256), 0, stream,
                       xl_bf, xr_bf, rowptr2, ssrc, att, bias, out);
}